// Round 4
// baseline (886.112 us; speedup 1.0000x reference)
//
#include <hip/hip_runtime.h>

// Correlation-1D: out[b,d,h,w] = sum_c x1[b,c,h,w] * x2pad[b,c,h,w+d], d in [0,41)
// Shapes: x1,x2 [8,256,96,320] fp32 -> out [8,41,96,320] fp32.
//
// R3 baseline (WT=4, 320thr): 290us, SQ_LDS_BANK_CONFLICT=7.2e7 (~18 extra
// cyc per ds_read_b128), VALUBusy 23%, HBM 1TB/s -> LDS-pipe-bound.
// R4 change: WT=8 per thread (8w x 12d = 96 acc) -> window is 20 floats =
// 5x ds_read_b128 per 96 FMAs (was 4 per 48): 1.6x less LDS traffic, 2x more
// FMA per read for latency hiding. Block = 160 threads (WG=40 x DG=4), one
// (b,h) row per block, grid 768 = 3 blocks/CU resident.

#define C_    256
#define H_    96
#define W_    320
#define D_    41
#define CC_   8
#define NCH_  (C_ / CC_)      // 32 chunks
#define WG_   40              // w-groups (WT=8)
#define DG_   4               // d-groups (DT=12, covers 48, tail masked)
#define NTHR_ (WG_ * DG_)     // 160 threads
#define LROW_ 368             // 20 zero | 320 data | 28 zero  (16B-aligned rows)
#define CHW_  (H_ * W_)       // 30720

__global__ __launch_bounds__(NTHR_) void corr1d_kernel(
    const float* __restrict__ x1, const float* __restrict__ x2,
    float* __restrict__ out)
{
    __shared__ float sx2[2][CC_][LROW_];

    const int t  = threadIdx.x;
    const int tw = t % WG_;         // 0..39
    const int td = t / WG_;         // 0..3
    const int b  = blockIdx.x / H_;
    const int h  = blockIdx.x % H_;

    // Zero the pad regions of both buffers once (never overwritten).
    for (int i = t; i < 2 * CC_ * 48; i += NTHR_) {
        int buf = i / (CC_ * 48);
        int rem = i - buf * (CC_ * 48);
        int row = rem / 48;
        int p   = rem - row * 48;
        int idx = (p < 20) ? p : (320 + p);   // p=20..47 -> 340..367
        sx2[buf][row][idx] = 0.0f;
    }

    const int base = b * C_ * CHW_ + h * W_;  // + c*CHW_ + w
    const int w8   = 8 * tw;                  // x1/out w start
    const int s4   = w8 + 12 * td;            // x2 window start (16B aligned)

    // Staging: 8 rows x 320 floats = 640 float4; 160 threads x 4 each.
    // i = t + 160k: row = i/80, col4 = i%80 -> perfectly coalesced.
    float4 st[4];
#pragma unroll
    for (int k = 0; k < 4; ++k) {
        int i = t + NTHR_ * k;
        int row = i / 80, c4 = (i % 80) * 4;
        st[k] = *(const float4*)(x2 + base + row * CHW_ + c4);
    }
#pragma unroll
    for (int k = 0; k < 4; ++k) {
        int i = t + NTHR_ * k;
        int row = i / 80, c4 = (i % 80) * 4;
        *(float4*)(&sx2[0][row][20 + c4]) = st[k];
    }

    float acc[12][8];
#pragma unroll
    for (int dd = 0; dd < 12; ++dd)
#pragma unroll
        for (int i = 0; i < 8; ++i) acc[dd][i] = 0.0f;

    for (int k = 0; k < NCH_; ++k) {
        __syncthreads();   // prev writes -> this chunk's reads; and protects
                           // the other buffer (written below) from prev readers
        const int  cur  = k & 1;
        const bool more = (k + 1 < NCH_);
        if (more) {
            const int c0n = (k + 1) * CC_;
#pragma unroll
            for (int kk = 0; kk < 4; ++kk) {
                int i = t + NTHR_ * kk;
                int row = i / 80, c4 = (i % 80) * 4;
                st[kk] = *(const float4*)(x2 + base + (c0n + row) * CHW_ + c4);
            }
        }

        const float* __restrict__ bp = &sx2[cur][0][0];
        const int c0 = k * CC_;
#pragma unroll
        for (int cc = 0; cc < CC_; ++cc) {
            float4 a0 = *(const float4*)(x1 + base + (c0 + cc) * CHW_ + w8);
            float4 a1 = *(const float4*)(x1 + base + (c0 + cc) * CHW_ + w8 + 4);
            const float* r = bp + cc * LROW_ + s4;
            float4 q0 = *(const float4*)(r);
            float4 q1 = *(const float4*)(r + 4);
            float4 q2 = *(const float4*)(r + 8);
            float4 q3 = *(const float4*)(r + 12);
            float4 q4 = *(const float4*)(r + 16);
            float win[20] = {q0.x, q0.y, q0.z, q0.w, q1.x, q1.y, q1.z, q1.w,
                             q2.x, q2.y, q2.z, q2.w, q3.x, q3.y, q3.z, q3.w,
                             q4.x, q4.y, q4.z, q4.w};
            float av[8] = {a0.x, a0.y, a0.z, a0.w, a1.x, a1.y, a1.z, a1.w};
#pragma unroll
            for (int dd = 0; dd < 12; ++dd)
#pragma unroll
                for (int i = 0; i < 8; ++i)
                    acc[dd][i] = fmaf(av[i], win[dd + i], acc[dd][i]);
        }

        if (more) {
#pragma unroll
            for (int kk = 0; kk < 4; ++kk) {
                int i = t + NTHR_ * kk;
                int row = i / 80, c4 = (i % 80) * 4;
                *(float4*)(&sx2[cur ^ 1][row][20 + c4]) = st[kk];
            }
        }
    }

    // Store: d = 12*td + dd, skip the masked d >= 41 tail.
    const int ob = b * (D_ * CHW_) + h * W_ + w8;
#pragma unroll
    for (int dd = 0; dd < 12; ++dd) {
        const int d = 12 * td + dd;
        if (d < D_) {
            float4 o0, o1;
            o0.x = acc[dd][0]; o0.y = acc[dd][1];
            o0.z = acc[dd][2]; o0.w = acc[dd][3];
            o1.x = acc[dd][4]; o1.y = acc[dd][5];
            o1.z = acc[dd][6]; o1.w = acc[dd][7];
            *(float4*)(out + ob + d * CHW_)     = o0;
            *(float4*)(out + ob + d * CHW_ + 4) = o1;
        }
    }
}

extern "C" void kernel_launch(void* const* d_in, const int* in_sizes, int n_in,
                              void* d_out, int out_size, void* d_ws, size_t ws_size,
                              hipStream_t stream)
{
    const float* x1 = (const float*)d_in[0];
    const float* x2 = (const float*)d_in[1];
    float* out      = (float*)d_out;
    const int B     = in_sizes[0] / (C_ * CHW_);   // 8
    corr1d_kernel<<<dim3(B * H_), dim3(NTHR_), 0, stream>>>(x1, x2, out);
}

// Round 5
// 740.836 us; speedup vs baseline: 1.1961x; 1.1961x over previous
//
#include <hip/hip_runtime.h>

// Correlation-1D: out[b,d,h,w] = sum_c x1[b,c,h,w] * x2pad[b,c,h,w+d], d in [0,41)
// Shapes: x1,x2 [8,256,96,320] fp32 -> out [8,41,96,320] fp32.
//
// History:
//  R3 (WT=4, t=td*80+tw): 290us. Waves 1-4 mixed td -> window starts offset
//     48B -> same-bank/diff-addr conflicts: 7.2e7 (~18 extra cyc per b128).
//  R4 (WT=8): 561us. 32B lane stride per b128 -> worse (8.7e7). REVERTED.
//  R5: wave-PURE mapping. Waves 0..3: td=wid, lanes=64 consecutive w-groups,
//     window reads are dense 16B-stride 1024B wave reads (m134-clean, 12cyc).
//     Wave 4 handles the W=320 remainder (w 256..319) for all 4 td.
// LDS floor ~87us/CU ~= HBM floor 86us -> target 110-145us.

#define C_    256
#define H_    96
#define W_    320
#define D_    41
#define CC_   8
#define NCH_  (C_ / CC_)      // 32 chunks
#define DT_   12              // d per td-group (4 groups -> 48, mask >=41)
#define NTHR_ 320             // 5 waves
#define LROW_ 368             // 20 zero | 320 data | 28 zero (16B-aligned rows)
#define CHW_  (H_ * W_)       // 30720

__global__ __launch_bounds__(NTHR_, 4) void corr1d_kernel(
    const float* __restrict__ x1, const float* __restrict__ x2,
    float* __restrict__ out)
{
    __shared__ float sx2[2][CC_][LROW_];

    const int t    = threadIdx.x;
    const int wid  = t >> 6;        // 0..4
    const int lane = t & 63;
    const int b    = blockIdx.x / H_;
    const int h    = blockIdx.x % H_;

    // Zero the pad regions of both buffers once (never overwritten).
    for (int i = t; i < 2 * CC_ * 48; i += NTHR_) {
        int buf = i / (CC_ * 48);
        int rem = i - buf * (CC_ * 48);
        int row = rem / 48;
        int p   = rem - row * 48;
        int idx = (p < 20) ? p : (320 + p);   // p=20..47 -> 340..367
        sx2[buf][row][idx] = 0.0f;
    }

    // Thread coords: waves 0..3 td-pure over w 0..255; wave 4 = remainder.
    int td, w0;
    if (wid < 4) { td = wid;       w0 = 4 * lane; }            // dense wave read
    else         { td = lane >> 4; w0 = 256 + 4 * (lane & 15); }
    const int s4 = w0 + DT_ * td;   // window start; %4==0 -> b128-aligned

    const int base = b * C_ * CHW_ + h * W_;  // + c*CHW_ + w

    // Staging: 8 rows x 80 float4 = 640 float4 by 320 threads x 2.
    float4 st[2];
#pragma unroll
    for (int k = 0; k < 2; ++k) {
        int i = t + NTHR_ * k;
        int row = i / 80, c4 = (i % 80) * 4;
        st[k] = *(const float4*)(x2 + base + row * CHW_ + c4);
    }
#pragma unroll
    for (int k = 0; k < 2; ++k) {
        int i = t + NTHR_ * k;
        int row = i / 80, c4 = (i % 80) * 4;
        *(float4*)(&sx2[0][row][20 + c4]) = st[k];
    }

    float acc[DT_][4];
#pragma unroll
    for (int dd = 0; dd < DT_; ++dd)
#pragma unroll
        for (int i = 0; i < 4; ++i) acc[dd][i] = 0.0f;

    for (int k = 0; k < NCH_; ++k) {
        __syncthreads();   // prev writes -> this chunk's reads; also protects
                           // the other buffer (written below) from prev readers
        const int  cur  = k & 1;
        const bool more = (k + 1 < NCH_);
        if (more) {
            const int c0n = (k + 1) * CC_;
#pragma unroll
            for (int kk = 0; kk < 2; ++kk) {
                int i = t + NTHR_ * kk;
                int row = i / 80, c4 = (i % 80) * 4;
                st[kk] = *(const float4*)(x2 + base + (c0n + row) * CHW_ + c4);
            }
        }

        const float* __restrict__ bp = &sx2[cur][0][0];
        const int c0 = k * CC_;
#pragma unroll
        for (int cc = 0; cc < CC_; ++cc) {
            float4 a = *(const float4*)(x1 + base + (c0 + cc) * CHW_ + w0);
            const float* r = bp + cc * LROW_ + s4;
            float4 q0 = *(const float4*)(r);
            float4 q1 = *(const float4*)(r + 4);
            float4 q2 = *(const float4*)(r + 8);
            float4 q3 = *(const float4*)(r + 12);
            float win[16] = {q0.x, q0.y, q0.z, q0.w, q1.x, q1.y, q1.z, q1.w,
                             q2.x, q2.y, q2.z, q2.w, q3.x, q3.y, q3.z, q3.w};
            float av[4] = {a.x, a.y, a.z, a.w};
#pragma unroll
            for (int dd = 0; dd < DT_; ++dd)
#pragma unroll
                for (int i = 0; i < 4; ++i)
                    acc[dd][i] = fmaf(av[i], win[dd + i], acc[dd][i]);
        }

        if (more) {
#pragma unroll
            for (int kk = 0; kk < 2; ++kk) {
                int i = t + NTHR_ * kk;
                int row = i / 80, c4 = (i % 80) * 4;
                *(float4*)(&sx2[cur ^ 1][row][20 + c4]) = st[kk];
            }
        }
    }

    // Store: d = DT_*td + dd, skip masked d >= 41.
    const int ob = b * (D_ * CHW_) + h * W_ + w0;
#pragma unroll
    for (int dd = 0; dd < DT_; ++dd) {
        const int d = DT_ * td + dd;
        if (d < D_) {
            float4 o;
            o.x = acc[dd][0]; o.y = acc[dd][1];
            o.z = acc[dd][2]; o.w = acc[dd][3];
            *(float4*)(out + ob + d * CHW_) = o;
        }
    }
}

extern "C" void kernel_launch(void* const* d_in, const int* in_sizes, int n_in,
                              void* d_out, int out_size, void* d_ws, size_t ws_size,
                              hipStream_t stream)
{
    const float* x1 = (const float*)d_in[0];
    const float* x2 = (const float*)d_in[1];
    float* out      = (float*)d_out;
    const int B     = in_sizes[0] / (C_ * CHW_);   // 8
    corr1d_kernel<<<dim3(B * H_), dim3(NTHR_), 0, stream>>>(x1, x2, out);
}